// Round 9
// baseline (234.149 us; speedup 1.0000x reference)
//
#include <hip/hip_runtime.h>
#include <hip/hip_bf16.h>
#include <hip/hip_fp16.h>
#include <math.h>

typedef __hip_bfloat16 bf16;
#define NEG_SLOPE 0.2f

typedef _Float16 f16x8 __attribute__((ext_vector_type(8)));
typedef float f32x4 __attribute__((ext_vector_type(4)));

#define NSEG 25
struct Seg { const void* src; int n; int off; };
struct Tab { Seg s[NSEG]; };

__device__ __forceinline__ float ldconv(const void* src, int i, int f32mode) {
    return f32mode ? ((const float*)src)[i]
                   : __bfloat162float(((const bf16*)src)[i]);
}

// ====== merged: convert+CSR (blocks < CB) | embed+conv1 (blocks >= CB) ======
// The two halves have NO data dependency: embed reads raw weights with inline
// ldconv (bit-identical to pre-converted values) and recomputes the 4KB dtype
// census locally. They co-reside and overlap.
__launch_bounds__(256)
__global__ void k_convembed(Tab tab, float* __restrict__ dst,
                            const unsigned short* __restrict__ xdet, int* __restrict__ flag,
                            const int* __restrict__ srcArr, const int* __restrict__ dstArr,
                            int E, int N,
                            int* __restrict__ deg, int* __restrict__ csrF,
                            int* __restrict__ spillD, int* __restrict__ spillS,
                            int* __restrict__ spillCnt,
                            const void* a2WlS, const void* a2WrS,
                            const void* gWlS, const void* gWrS,
                            __half* __restrict__ a2Wlt, __half* __restrict__ a2Wrt,
                            __half* __restrict__ gWlt, __half* __restrict__ gWrt,
                            const void* __restrict__ xraw,
                            const void* aeWr, const void* aebr,
                            const void* Wlr, const void* blr,
                            const void* Wrr, const void* brr,
                            __half* __restrict__ outl, float* __restrict__ outr,
                            int CB) {
    // local dtype census (cheap, L2-hot; same verdict in every block)
    __shared__ int cnt;
    if (threadIdx.x == 0) cnt = 0;
    __syncthreads();
    {
        int local = 0;
        for (int i = threadIdx.x; i < 2048; i += blockDim.x) {
            unsigned short w = xdet[2 * i];
            int e = (w >> 7) & 0xFF;
            if (e >= 0x90) local++;
        }
        atomicAdd(&cnt, local);
    }
    __syncthreads();
    int f32m = (cnt > 100) ? 1 : 0;
    if (blockIdx.x == 0 && threadIdx.x == 0) flag[0] = f32m;

    if (blockIdx.x < CB) {
        // ---------- convert weights + direct fixed-stride CSR build ----------
        int gid = blockIdx.x * blockDim.x + threadIdx.x;
        int gsz = CB * blockDim.x;
        for (int s = 0; s < NSEG; s++) {
            Seg sg = tab.s[s];
            for (int i = gid; i < sg.n; i += gsz)
                dst[sg.off + i] = ldconv(sg.src, i, f32m);
        }
        for (int i = gid; i < 128 * 128; i += gsz) {
            int k = i >> 7, j = i & 127;
            a2Wlt[(size_t)j * 128 + k] = __float2half(ldconv(a2WlS, i, f32m));
            a2Wrt[(size_t)j * 128 + k] = __float2half(ldconv(a2WrS, i, f32m));
        }
        for (int i = gid; i < 128 * 32; i += gsz) {
            int k = i >> 5, j = i & 31;
            gWlt[(size_t)j * 128 + k] = __float2half(ldconv(gWlS, i, f32m));
            gWrt[(size_t)j * 128 + k] = __float2half(ldconv(gWrS, i, f32m));
        }
        int EA = E + N;
        for (int e = gid; e < EA; e += gsz) {
            int d, s;
            if (e < E) { d = dstArr[e]; s = srcArr[e]; } else { d = s = e - E; }
            int r = atomicAdd(&deg[d], 1);
            if (r < 64) {
                csrF[(size_t)d * 64 + r] = s;
            } else {
                int o = atomicAdd(spillCnt, 1);
                spillD[o] = d; spillS[o] = s;
            }
        }
        return;
    }
    // ---------- embed + conv1 linear for 32 nodes (raw weights inline) ----------
    __shared__ float xs[100 * 36];
    __shared__ float axs[32 * 36];
    constexpr int NTP = 36;
    int t = threadIdx.x, nb = (blockIdx.x - CB) * 32;
    if (f32m) {
        const float4* x4 = (const float4*)xraw;
        for (int idx = t; idx < 32 * 25; idx += 256) {
            int node = idx / 25, k4 = idx % 25;
            float4 v = x4[(size_t)(nb + node) * 25 + k4];
            xs[(k4 * 4 + 0) * NTP + node] = v.x;
            xs[(k4 * 4 + 1) * NTP + node] = v.y;
            xs[(k4 * 4 + 2) * NTP + node] = v.z;
            xs[(k4 * 4 + 3) * NTP + node] = v.w;
        }
    } else {
        const ushort4* xu = (const ushort4*)xraw;
        for (int idx = t; idx < 32 * 25; idx += 256) {
            int node = idx / 25, k4 = idx % 25;
            ushort4 u = xu[(size_t)(nb + node) * 25 + k4];
            xs[(k4 * 4 + 0) * NTP + node] = __uint_as_float((unsigned)u.x << 16);
            xs[(k4 * 4 + 1) * NTP + node] = __uint_as_float((unsigned)u.y << 16);
            xs[(k4 * 4 + 2) * NTP + node] = __uint_as_float((unsigned)u.z << 16);
            xs[(k4 * 4 + 3) * NTP + node] = __uint_as_float((unsigned)u.w << 16);
        }
    }
    __syncthreads();
    {
        int j = t & 31, g0 = t >> 5;
        float a0 = 0.f, a1 = 0.f, a2 = 0.f, a3 = 0.f;
        #pragma unroll 10
        for (int k = 0; k < 100; k++) {
            float w = ldconv(aeWr, k * 32 + j, f32m);
            const float4 xv = *(const float4*)&xs[k * NTP + g0 * 4];
            a0 += w * xv.x; a1 += w * xv.y; a2 += w * xv.z; a3 += w * xv.w;
        }
        float bj = ldconv(aebr, j, f32m);
        axs[j * NTP + g0 * 4 + 0] = fmaxf(a0 + bj, 0.f);
        axs[j * NTP + g0 * 4 + 1] = fmaxf(a1 + bj, 0.f);
        axs[j * NTP + g0 * 4 + 2] = fmaxf(a2 + bj, 0.f);
        axs[j * NTP + g0 * 4 + 3] = fmaxf(a3 + bj, 0.f);
    }
    __syncthreads();
    {
        int j = t & 63, g0 = t >> 6;
        float aL0[2][4], aL1[2][4], aR0[2][4], aR1[2][4];
        #pragma unroll
        for (int g = 0; g < 2; g++)
            #pragma unroll
            for (int c = 0; c < 4; c++) { aL0[g][c]=0.f; aL1[g][c]=0.f; aR0[g][c]=0.f; aR1[g][c]=0.f; }
        #pragma unroll 4
        for (int k = 0; k < 32; k++) {
            float wl0 = ldconv(Wlr, k * 128 + j, f32m);
            float wl1 = ldconv(Wlr, k * 128 + j + 64, f32m);
            float wr0 = ldconv(Wrr, k * 128 + j, f32m);
            float wr1 = ldconv(Wrr, k * 128 + j + 64, f32m);
            #pragma unroll
            for (int g = 0; g < 2; g++) {
                const float4 xv = *(const float4*)&axs[k * NTP + (g0 + g * 4) * 4];
                aL0[g][0] += wl0 * xv.x; aL0[g][1] += wl0 * xv.y; aL0[g][2] += wl0 * xv.z; aL0[g][3] += wl0 * xv.w;
                aL1[g][0] += wl1 * xv.x; aL1[g][1] += wl1 * xv.y; aL1[g][2] += wl1 * xv.z; aL1[g][3] += wl1 * xv.w;
                aR0[g][0] += wr0 * xv.x; aR0[g][1] += wr0 * xv.y; aR0[g][2] += wr0 * xv.z; aR0[g][3] += wr0 * xv.w;
                aR1[g][0] += wr1 * xv.x; aR1[g][1] += wr1 * xv.y; aR1[g][2] += wr1 * xv.z; aR1[g][3] += wr1 * xv.w;
            }
        }
        float bl0 = ldconv(blr, j, f32m), bl1 = ldconv(blr, j + 64, f32m);
        float br0 = ldconv(brr, j, f32m), br1 = ldconv(brr, j + 64, f32m);
        #pragma unroll
        for (int g = 0; g < 2; g++) {
            int n0 = nb + (g0 + g * 4) * 4;
            #pragma unroll
            for (int c = 0; c < 4; c++) {
                size_t row = (size_t)(n0 + c) * 128;
                outl[row + j]      = __float2half(aL0[g][c] + bl0);
                outl[row + j + 64] = __float2half(aL1[g][c] + bl1);
                outr[row + j]      = aR0[g][c] + br0;
                outr[row + j + 64] = aR1[g][c] + br1;
            }
        }
    }
}

// ====== per-edge math (16-lane group, 8 channels/lane) =======================
__device__ __forceinline__ void gat_proc(float4 raw, bool valid,
                                         const float* xrd, const float* av,
                                         float* acc, float& sm) {
    const __half2* h = (const __half2*)&raw;
    float v[8];
    float2 f;
    f = __half22float2(h[0]); v[0] = f.x; v[1] = f.y;
    f = __half22float2(h[1]); v[2] = f.x; v[3] = f.y;
    f = __half22float2(h[2]); v[4] = f.x; v[5] = f.y;
    f = __half22float2(h[3]); v[6] = f.x; v[7] = f.y;
    float p = 0.f;
    #pragma unroll
    for (int c = 0; c < 8; c++) {
        float u = v[c] + xrd[c];
        u = (u > 0.f) ? u : NEG_SLOPE * u;
        p += u * av[c];
    }
    p += __shfl_xor(p, 1);
    p += __shfl_xor(p, 2);
    p += __shfl_xor(p, 4);
    p += __shfl_xor(p, 8);
    float w = __expf(fminf(p, 80.f));
    if (!valid) w = 0.f;
    sm += w;
    #pragma unroll
    for (int c = 0; c < 8; c++) acc[c] += w * v[c];
}

// ====== GAT H=4 gather of ONE dst per 16-lane group into LDS row `node` =====
// Fixed-stride CSR: row base = d*64, count = deg[d]; spill path for deg>64
// (correctness only; never taken on this input). d < 0 => zeros written.
// xsh layout: xsh[node * 136 + ch], node in [0,16), ch in [0,128). 4.35 KB.
__device__ __forceinline__ void gat16_to_lds(__half* xsh,
                                             const __half* __restrict__ xl,
                                             const float* __restrict__ xr,
                                             const float* __restrict__ att,
                                             const int* __restrict__ deg,
                                             const int* __restrict__ csrF,
                                             const int* __restrict__ spillD,
                                             const int* __restrict__ spillS,
                                             const int* __restrict__ spillCnt,
                                             const float* __restrict__ bias,
                                             int d, int node) {
    int t = threadIdx.x;
    int lane = t & 63;
    int sub = lane & 15;                      // lane within group
    int lb = lane & 48;                       // group base lane
    float av[8];
    {
        const float4* t4 = (const float4*)(att + sub * 8);
        float4 c = t4[0], e = t4[1];
        av[0]=c.x; av[1]=c.y; av[2]=c.z; av[3]=c.w;
        av[4]=e.x; av[5]=e.y; av[6]=e.z; av[7]=e.w;
    }
    bool ok = d >= 0;
    int cnt = ok ? deg[d] : 0;
    int cmain = cnt < 64 ? cnt : 64;
    size_t i0 = (size_t)(ok ? d : 0) * 64;

    float xrd[8];
    #pragma unroll
    for (int c = 0; c < 8; c++) xrd[c] = 0.f;
    if (ok) {
        const float4* p4 = (const float4*)(xr + (size_t)d * 128 + sub * 8);
        float4 a = p4[0], b = p4[1];
        xrd[0]=a.x; xrd[1]=a.y; xrd[2]=a.z; xrd[3]=a.w;
        xrd[4]=b.x; xrd[5]=b.y; xrd[6]=b.z; xrd[7]=b.w;
    }
    float acc[8];
    #pragma unroll
    for (int c = 0; c < 8; c++) acc[c] = 0.f;
    float sm = 0.f;

    // first csr chunk (16 edges, one coalesced 64B load per group)
    int myv = (sub < cmain) ? csrF[i0 + sub] : 0;
    for (int c0 = 0; c0 < cmain; c0 += 16) {
        // prefetch next chunk's indices while processing current
        int myv_nxt = (c0 + 16 + sub < cmain) ? csrF[i0 + c0 + 16 + sub] : 0;
        int rem = min(cmain - c0, 16);
        for (int k = 0; k < rem; k += 4) {
            int s0 = __shfl(myv, lb + k + 0);
            int s1 = __shfl(myv, lb + k + 1);
            int s2 = __shfl(myv, lb + k + 2);
            int s3 = __shfl(myv, lb + k + 3);
            float4 r0 = *(const float4*)(xl + (size_t)s0 * 128 + sub * 8);
            float4 r1 = *(const float4*)(xl + (size_t)s1 * 128 + sub * 8);
            float4 r2 = *(const float4*)(xl + (size_t)s2 * 128 + sub * 8);
            float4 r3 = *(const float4*)(xl + (size_t)s3 * 128 + sub * 8);
            gat_proc(r0, true,        xrd, av, acc, sm);
            gat_proc(r1, k + 1 < rem, xrd, av, acc, sm);
            gat_proc(r2, k + 2 < rem, xrd, av, acc, sm);
            gat_proc(r3, k + 3 < rem, xrd, av, acc, sm);
        }
        myv = myv_nxt;
    }
    // rare spill path (deg > 64): linear scan of the overflow list
    if (cnt > 64) {
        int stot = *spillCnt;
        for (int j = 0; j < stot; j++) {
            if (spillD[j] == d) {
                float4 r = *(const float4*)(xl + (size_t)spillS[j] * 128 + sub * 8);
                gat_proc(r, true, xrd, av, acc, sm);
            }
        }
    }

    // acc is already the full per-dst sum (group's 16 lanes cover 128 ch)
    int ch = sub * 8;
    if (ok) {
        float inv = 1.f / (sm + 1e-16f);
        #pragma unroll
        for (int c = 0; c < 8; c += 2) {
            __half2 hv;
            hv.x = __float2half(fmaxf(acc[c]     * inv + bias[ch + c],     0.f));
            hv.y = __float2half(fmaxf(acc[c + 1] * inv + bias[ch + c + 1], 0.f));
            *(__half2*)&xsh[node * 136 + ch + c] = hv;
        }
    } else {
        // keep MFMA inputs clean for unused rows
        #pragma unroll
        for (int c = 0; c < 8; c += 2)
            *(__half2*)&xsh[node * 136 + ch + c] = __half2{__half(0.f), __half(0.f)};
    }
}

// ====== fused: conv1 gather (16-dst tile) -> conv2 dual linear via MFMA ======
__launch_bounds__(256)
__global__ void k_gatlin(const __half* __restrict__ xl, const float* __restrict__ xr,
                         const float* __restrict__ att,
                         const int* __restrict__ deg, const int* __restrict__ csrF,
                         const int* __restrict__ spillD, const int* __restrict__ spillS,
                         const int* __restrict__ spillCnt,
                         const float* __restrict__ bias,
                         const __half* __restrict__ Wlt, const float* __restrict__ bl,
                         const __half* __restrict__ Wrt, const float* __restrict__ br,
                         __half* __restrict__ outl, float* __restrict__ outr, int N) {
    __shared__ __align__(16) __half xsh[16 * 136];
    int nb = blockIdx.x * 16;
    int t = threadIdx.x;
    int lane = t & 63, wv = t >> 6;
    int quad = lane >> 4, n16 = lane & 15;
    {
        int node = wv * 4 + quad;
        int dd = nb + node;
        gat16_to_lds(xsh, xl, xr, att, deg, csrF, spillD, spillS, spillCnt,
                     bias, (dd < N) ? dd : -1, node);
    }
    __syncthreads();

    // A fragments: A[m=lane&15][k=quad*8+i], 4 k-tiles of 32
    f16x8 a[4];
    #pragma unroll
    for (int kt = 0; kt < 4; kt++)
        a[kt] = *(const f16x8*)&xsh[n16 * 136 + kt * 32 + quad * 8];

    int j0 = wv * 32;   // this wave's 32 output columns (two 16-tiles), for L and R
    f32x4 aL0 = {0.f,0.f,0.f,0.f}, aL1 = {0.f,0.f,0.f,0.f};
    f32x4 aR0 = {0.f,0.f,0.f,0.f}, aR1 = {0.f,0.f,0.f,0.f};
    #pragma unroll
    for (int kt = 0; kt < 4; kt++) {
        int ko = kt * 32 + quad * 8;
        f16x8 b0 = *(const f16x8*)&Wlt[(size_t)(j0 + n16) * 128 + ko];
        f16x8 b1 = *(const f16x8*)&Wlt[(size_t)(j0 + 16 + n16) * 128 + ko];
        f16x8 b2 = *(const f16x8*)&Wrt[(size_t)(j0 + n16) * 128 + ko];
        f16x8 b3 = *(const f16x8*)&Wrt[(size_t)(j0 + 16 + n16) * 128 + ko];
        aL0 = __builtin_amdgcn_mfma_f32_16x16x32_f16(a[kt], b0, aL0, 0, 0, 0);
        aL1 = __builtin_amdgcn_mfma_f32_16x16x32_f16(a[kt], b1, aL1, 0, 0, 0);
        aR0 = __builtin_amdgcn_mfma_f32_16x16x32_f16(a[kt], b2, aR0, 0, 0, 0);
        aR1 = __builtin_amdgcn_mfma_f32_16x16x32_f16(a[kt], b3, aR1, 0, 0, 0);
    }
    float blj0 = bl[j0 + n16], blj1 = bl[j0 + 16 + n16];
    float brj0 = br[j0 + n16], brj1 = br[j0 + 16 + n16];
    #pragma unroll
    for (int r = 0; r < 4; r++) {
        int node = quad * 4 + r;        // D row = node
        if (nb + node >= N) continue;
        size_t row = (size_t)(nb + node) * 128;
        outl[row + j0 + n16]      = __float2half(aL0[r] + blj0);
        outl[row + j0 + 16 + n16] = __float2half(aL1[r] + blj1);
        outr[row + j0 + n16]      = aR0[r] + brj0;
        outr[row + j0 + 16 + n16] = aR1[r] + brj1;
    }
}

// ====== fused: per-focal conv2 gather + global linear (LDS) + tail head ======
// One block per focal b. Slot 0 = focal f (for xr_g); slots 1..cf = f's
// sources (for xl_g). All global-feature values live only in LDS: no Lbuf,
// no global round-trip, no separate tail kernel. Edge partition/order in the
// tail matches the old k_tailf exactly (j % 8 == grp, ascending).
__launch_bounds__(256)
__global__ void k_gatfuse(const __half* __restrict__ xl, const float* __restrict__ xr,
                          const float* __restrict__ att,
                          const int* __restrict__ deg, const int* __restrict__ csrF,
                          const int* __restrict__ spillD, const int* __restrict__ spillS,
                          const int* __restrict__ spillCnt,
                          const float* __restrict__ bias,
                          const __half* __restrict__ Wlt, const float* __restrict__ bl,
                          const __half* __restrict__ Wrt, const float* __restrict__ br,
                          const float* __restrict__ gatt, const float* __restrict__ gb,
                          const int* __restrict__ focal,
                          const float* __restrict__ clf, const float* __restrict__ clW,
                          const float* __restrict__ clb, const float* __restrict__ fcW,
                          const float* __restrict__ fcb, void* __restrict__ out,
                          const int* __restrict__ flag) {
    __shared__ __align__(16) __half xsh[16 * 136];
    __shared__ __align__(16) __half glx[64][32];    // xl_g of chunk slots
    __shared__ float xrf[32];                        // xr_g of focal
    __shared__ int slotbuf[64];
    __shared__ int spillCur;
    __shared__ float comb[64];
    __shared__ float ssb[2];

    int b = blockIdx.x;
    int f = focal[b];
    int cf = deg[f];
    int cm = cf < 64 ? cf : 64;
    int t = threadIdx.x;
    int lane = t & 63, wv = t >> 6;
    int quad = lane >> 4, n16 = lane & 15;
    if (t == 0) spillCur = 0;

    // ---- phase 0: xr_g[f] -> xrf (slot-0-only tile; same MFMA as before) ----
    {
        int node = wv * 4 + quad;
        gat16_to_lds(xsh, xl, xr, att, deg, csrF, spillD, spillS, spillCnt,
                     bias, (node == 0) ? f : -1, node);
        __syncthreads();
        f16x8 a[4];
        #pragma unroll
        for (int kt = 0; kt < 4; kt++)
            a[kt] = *(const f16x8*)&xsh[n16 * 136 + kt * 32 + quad * 8];
        if (wv >= 2) {
            int j0 = (wv & 1) * 16;
            f32x4 accv = {0.f,0.f,0.f,0.f};
            #pragma unroll
            for (int kt = 0; kt < 4; kt++) {
                f16x8 bb = *(const f16x8*)&Wrt[(size_t)(j0 + n16) * 128 + kt * 32 + quad * 8];
                accv = __builtin_amdgcn_mfma_f32_16x16x32_f16(a[kt], bb, accv, 0, 0, 0);
            }
            if (quad == 0) xrf[j0 + n16] = accv[0] + br[j0 + n16];  // row 0 = slot 0
        }
        __syncthreads();
    }

    // ---- tail accumulator state (threads 0..63 = wave 0) ----
    int grp = t >> 3, sub8 = t & 7;
    float xrd4[4], av4[4], acc4[4];
    float sm = 0.f;
    if (t < 64) {
        float4 a = *(const float4*)&xrf[sub8 * 4];
        xrd4[0]=a.x; xrd4[1]=a.y; xrd4[2]=a.z; xrd4[3]=a.w;
        float4 c = *(const float4*)(gatt + sub8 * 4);
        av4[0]=c.x; av4[1]=c.y; av4[2]=c.z; av4[3]=c.w;
        #pragma unroll
        for (int c2 = 0; c2 < 4; c2++) acc4[c2] = 0.f;
    }

    // ---- chunks of up to 64 sources: gather+linear -> glx, then accumulate --
    for (int c0 = 0; c0 < cf; c0 += 64) {
        int cn = cf - c0; if (cn > 64) cn = 64;
        __syncthreads();                      // glx/slotbuf reuse guard
        if (t < cn && c0 + t < cm) slotbuf[t] = csrF[(size_t)f * 64 + c0 + t];
        __syncthreads();
        if (t == 0 && c0 + cn > cm) {         // rare: fill tail slots from spill
            int k = cm - c0; if (k < 0) k = 0;
            int stot = *spillCnt;
            while (k < cn) {
                while (spillCur < stot && spillD[spillCur] != f) spillCur++;
                if (spillCur < stot) slotbuf[k++] = spillS[spillCur++];
                else slotbuf[k++] = f;        // unreachable; keep defined
            }
        }
        __syncthreads();
        for (int tb = 0; tb < cn; tb += 16) {
            int node = wv * 4 + quad;
            int si = tb + node;
            int d = (si < cn) ? slotbuf[si] : -1;
            gat16_to_lds(xsh, xl, xr, att, deg, csrF, spillD, spillS, spillCnt,
                         bias, d, node);
            __syncthreads();
            f16x8 a[4];
            #pragma unroll
            for (int kt = 0; kt < 4; kt++)
                a[kt] = *(const f16x8*)&xsh[n16 * 136 + kt * 32 + quad * 8];
            if (wv < 2) {                     // L-side only (xl_g), 2 waves cover 32 cols
                int j0 = (wv & 1) * 16;
                f32x4 accv = {0.f,0.f,0.f,0.f};
                #pragma unroll
                for (int kt = 0; kt < 4; kt++) {
                    f16x8 bb = *(const f16x8*)&Wlt[(size_t)(j0 + n16) * 128 + kt * 32 + quad * 8];
                    accv = __builtin_amdgcn_mfma_f32_16x16x32_f16(a[kt], bb, accv, 0, 0, 0);
                }
                float bj = bl[j0 + n16];
                #pragma unroll
                for (int r = 0; r < 4; r++)
                    glx[tb + quad * 4 + r][j0 + n16] = __float2half(accv[r] + bj);
            }
            __syncthreads();
        }
        // tail accumulation over this chunk (same partition as old k_tailf)
        if (t < 64) {
            for (int j = c0 + grp; j < c0 + cn; j += 8) {
                float2 raw = *(const float2*)&glx[j - c0][sub8 * 4];
                const __half2* h = (const __half2*)&raw;
                float v[4];
                float2 fx;
                fx = __half22float2(h[0]); v[0] = fx.x; v[1] = fx.y;
                fx = __half22float2(h[1]); v[2] = fx.x; v[3] = fx.y;
                float p = 0.f;
                #pragma unroll
                for (int c = 0; c < 4; c++) {
                    float u = v[c] + xrd4[c];
                    u = (u > 0.f) ? u : NEG_SLOPE * u;
                    p += u * av4[c];
                }
                p += __shfl_xor(p, 1);
                p += __shfl_xor(p, 2);
                p += __shfl_xor(p, 4);
                float w = __expf(fminf(p, 80.f));
                sm += w;
                #pragma unroll
                for (int c = 0; c < 4; c++) acc4[c] += w * v[c];
            }
        }
    }
    __syncthreads();

    // ---- merge 8 edge-groups (threads 0..63 are one wave) + output head ----
    if (t < 64) {
        sm += __shfl_xor(sm, 8); sm += __shfl_xor(sm, 16); sm += __shfl_xor(sm, 32);
        #pragma unroll
        for (int c = 0; c < 4; c++) {
            acc4[c] += __shfl_xor(acc4[c], 8);
            acc4[c] += __shfl_xor(acc4[c], 16);
            acc4[c] += __shfl_xor(acc4[c], 32);
        }
        if (grp == 0) {
            float inv = 1.f / (sm + 1e-16f);
            #pragma unroll
            for (int c = 0; c < 4; c++)
                comb[sub8 * 4 + c] = fmaxf(acc4[c] * inv + gb[sub8 * 4 + c], 0.f);
        }
        if (t < 2) {
            float s = 0.f;
            for (int l = 0; l < 50; l++) s += clf[(size_t)b * 100 + l * 2 + t];
            ssb[t] = s / 50.f;
        }
    }
    __syncthreads();
    if (t < 32) comb[32 + t] = ssb[0] * clW[t] + ssb[1] * clW[32 + t] + clb[t];
    __syncthreads();
    if (t < 60) {
        float a2 = fcb[t];
        #pragma unroll 16
        for (int k = 0; k < 64; k++) a2 += comb[k] * fcW[k * 60 + t];
        if (flag[0]) ((float*)out)[b * 60 + t] = a2;
        else ((bf16*)out)[b * 60 + t] = __float2bfloat16(a2);
    }
}

extern "C" void kernel_launch(void* const* d_in, const int* in_sizes, int n_in,
                              void* d_out, int out_size, void* d_ws, size_t ws_size,
                              hipStream_t stream) {
    const int* edge  = (const int*)d_in[1];
    const int* focal = (const int*)d_in[5];

    const int N = in_sizes[0] / 100;   // 20000
    const int E = in_sizes[1] / 2;     // 320000
    const int B = in_sizes[5];         // 64
    const int EA = E + N;
    const int* srcArr = edge;
    const int* dstArr = edge + E;

    // ---- conversion table: weights + centerlines -> fp32 in ws (x stays raw)
    const int idxs[NSEG] = {7,8,9,10,11,12,13,14,15,16,17,18,19,20,
                            35,36,37,38,39,40,41,42,43,44, 6};
    float* base = (float*)d_ws;
    int* flag = (int*)base;            // base[0..15] reserved
    float* wf = base + 16;
    Tab tab;
    int off[NSEG];
    int o = 0;
    for (int i = 0; i < NSEG; i++) {
        tab.s[i].src = d_in[idxs[i]];
        tab.s[i].n   = in_sizes[idxs[i]];
        tab.s[i].off = o;
        off[i] = o;
        o += in_sizes[idxs[i]];
    }
    const float* a1att= wf + off[6],  *a1b  = wf + off[7];
    const float* a2bl = wf + off[9];
    const float* a2br = wf + off[11];
    const float* a2att= wf + off[12], *a2b  = wf + off[13];
    const float* clW  = wf + off[14], *clb  = wf + off[15];
    const float* gbl  = wf + off[17];
    const float* gbr  = wf + off[19];
    const float* gatt = wf + off[20], *gb   = wf + off[21];
    const float* fcW  = wf + off[22], *fcb  = wf + off[23];
    const float* clf  = wf + off[24];

    // ---- remaining workspace (keep 16B alignment) ----
    float* p = wf + o + ((4 - (o & 3)) & 3);
    size_t N128 = (size_t)N * 128;
    __half* hxl1 = (__half*)p;      p += (size_t)N * 64;    // conv1 xl fp16 [N,128]
    float* fB1  = p;                p += N128;              // conv1 xr fp32
    __half* hxl2 = (__half*)p;      p += (size_t)N * 64;    // conv2 xl fp16 [N,128]
    float* fB2  = p;                p += N128;              // conv2 xr fp32
    int* deg    = (int*)p;          // [N]
    int* st     = deg + N;          // [32] aux; st[29] = spillCnt
    int* csrF   = st + 32;          // [N*64] fixed-stride CSR
    int* spillD = csrF + (size_t)N * 64;  // [EA] overflow dsts (rare)
    int* spillS = spillD + EA;            // [EA] overflow srcs
    // transposed f16 weights (16B aligned)
    uintptr_t up = (uintptr_t)(spillS + EA);
    up = (up + 15) & ~(uintptr_t)15;
    __half* a2Wlt = (__half*)up;    // [128][128]
    __half* a2Wrt = a2Wlt + 16384;  // [128][128]
    __half* gWlt  = a2Wrt + 16384;  // [32][128]
    __half* gWrt  = gWlt + 4096;    // [32][128]
    int* spillCnt = st + 29;           // zeroed by the memset below

    const int CB = 256;                        // convert blocks
    const int EB = N / 32;                     // embed blocks (625)
    const int GT = (N + 15) / 16;              // gather+linear tiles (1250)

    // ---- zero deg + aux (spillCnt) via SDMA ----
    hipMemsetAsync(deg, 0, (size_t)(N + 32) * sizeof(int), stream);
    // ---- merged: convert+CSR (256 blocks) | embed+conv1 (625 blocks) ----
    k_convembed<<<CB + EB, 256, 0, stream>>>(tab, wf, (const unsigned short*)d_in[0],
                                             flag, srcArr, dstArr, E, N,
                                             deg, csrF, spillD, spillS, spillCnt,
                                             d_in[15], d_in[17], d_in[37], d_in[39],
                                             a2Wlt, a2Wrt, gWlt, gWrt,
                                             d_in[0], d_in[7], d_in[8],
                                             d_in[9], d_in[10], d_in[11], d_in[12],
                                             hxl1, fB1, CB);
    // ---- conv1 gather + conv2 linear (MFMA) -> hxl2/fB2 ----
    k_gatlin<<<GT, 256, 0, stream>>>(hxl1, fB1, a1att, deg, csrF,
                                     spillD, spillS, spillCnt, a1b,
                                     a2Wlt, a2bl, a2Wrt, a2br, hxl2, fB2, N);
    // ---- fused: per-focal conv2 gather + global linear (LDS) + tail head ----
    k_gatfuse<<<B, 256, 0, stream>>>(hxl2, fB2, a2att, deg, csrF,
                                     spillD, spillS, spillCnt, a2b,
                                     gWlt, gbl, gWrt, gbr, gatt, gb, focal,
                                     clf, clW, clb, fcW, fcb, d_out, flag);
}